// Round 8
// baseline (1995.076 us; speedup 1.0000x reference)
//
#include <hip/hip_runtime.h>
#include <hip/hip_bf16.h>

typedef __bf16 bf16;
typedef __bf16 bf16x4 __attribute__((ext_vector_type(4)));
typedef __bf16 bf16x8 __attribute__((ext_vector_type(8)));
typedef float floatx4 __attribute__((ext_vector_type(4)));

// ---- constants ----
#define Bb   2
#define Ss   2048
#define HID  2048
#define NH   16
#define HD   128
#define HG   8            // heads per pass

__device__ __forceinline__ float b2f(bf16 h) {
    unsigned short u = __builtin_bit_cast(unsigned short, h);
    unsigned int x = ((unsigned int)u) << 16;
    return __builtin_bit_cast(float, x);
}
__device__ __forceinline__ bf16 f2b(float f) {
    __hip_bfloat16 t = __float2bfloat16(f);
    return __builtin_bit_cast(bf16, t);
}
__device__ __forceinline__ bf16x8 load8_f32(const float* p) {
    float4 u = *(const float4*)p;
    float4 v = *(const float4*)(p + 4);
    bf16x8 r;
    r[0] = f2b(u.x); r[1] = f2b(u.y); r[2] = f2b(u.z); r[3] = f2b(u.w);
    r[4] = f2b(v.x); r[5] = f2b(v.y); r[6] = f2b(v.z); r[7] = f2b(v.w);
    return r;
}

// ---------------------------------------------------------------------------
// One pass: qkv GEMM + RoPE for (one batch, 8 heads) -> compact q/k/v
// [8][Ss][HD] bf16 in ws. grid=(16, 24): by = sec*8 + hl. block=256.
// ---------------------------------------------------------------------------
__global__ __launch_bounds__(256) void qkv_rope_pass(
    const float* __restrict__ xb,     // x of this batch [2048][2048] f32
    const float* __restrict__ W,      // w_qkv [6144][2048] f32
    const float* __restrict__ c0, const float* __restrict__ c1,
    bf16* __restrict__ qc, bf16* __restrict__ kc, bf16* __restrict__ vc,
    int hg)
{
    __shared__ bf16 tile[128][132];

    bool c0cos = (c0[0] > 0.5f);              // cos row0 == 1.0, sin row0 == 0.0
    const float* cosT = c0cos ? c0 : c1;
    const float* sinT = c0cos ? c1 : c0;

    int tid  = threadIdx.x;
    int lane = tid & 63;
    int wave = tid >> 6;
    int l15  = lane & 15;
    int quad = lane >> 4;

    int sec = blockIdx.y >> 3;                // 0=q 1=k 2=v
    int hl  = blockIdx.y & 7;                 // head within group
    int nbase = sec * (NH * HD) + (hg * HG + hl) * HD;
    int m0  = blockIdx.x * 128 + (wave >> 1) * 64;
    int n0l = (wave & 1) * 64;

    floatx4 acc[4][4] = {};
    const float* ap = xb + (size_t)(m0 + l15) * HID + quad * 8;
    const float* bp = W  + (size_t)(nbase + n0l + l15) * HID + quad * 8;

    for (int k0 = 0; k0 < HID; k0 += 32) {
        bf16x8 a[4], b[4];
#pragma unroll
        for (int i = 0; i < 4; i++) {
            a[i] = load8_f32(ap + (size_t)i * 16 * HID + k0);
            b[i] = load8_f32(bp + (size_t)i * 16 * HID + k0);
        }
#pragma unroll
        for (int i = 0; i < 4; i++)
#pragma unroll
            for (int j = 0; j < 4; j++)
                acc[i][j] = __builtin_amdgcn_mfma_f32_16x16x32_bf16(a[i], b[j], acc[i][j], 0, 0, 0);
    }

    int lr = (wave >> 1) * 64;
#pragma unroll
    for (int i = 0; i < 4; i++)
#pragma unroll
        for (int j = 0; j < 4; j++) {
            int row_l = lr + i * 16 + quad * 4;
            int col_l = n0l + j * 16 + l15;
#pragma unroll
            for (int r = 0; r < 4; r++)
                tile[row_l + r][col_l] = f2b(acc[i][j][r]);
        }
    __syncthreads();

    bf16* dst = (sec == 0) ? qc : (sec == 1) ? kc : vc;
    int d  = tid & 63;
    int r0 = tid >> 6;
#pragma unroll 4
    for (int it = 0; it < 32; it++) {
        int row_l = it * 4 + r0;
        int s = blockIdx.x * 128 + row_l;
        float x1 = b2f(tile[row_l][d]);
        float x2 = b2f(tile[row_l][d + 64]);
        size_t o = ((size_t)hl * Ss + s) * HD + d;
        if (sec == 2) {
            dst[o]      = f2b(x1);
            dst[o + 64] = f2b(x2);
        } else {
            float cc1 = cosT[s * HD + d];
            float ss1 = sinT[s * HD + d];
            float cc2 = cosT[s * HD + d + 64];
            float ss2 = sinT[s * HD + d + 64];
            dst[o]      = f2b(x1 * cc1 - x2 * ss1);
            dst[o + 64] = f2b(x2 * cc2 + x1 * ss2);
        }
    }
}

// ---------------------------------------------------------------------------
// Causal flash attention over compact q/k/v [8][Ss][HD]; bf16 ctx -> Obase
// (upper half of d_out used as ctx scratch), row stride HID.
// grid=(8, 32), block=256 (4 waves x 16 query rows).
// ---------------------------------------------------------------------------
__global__ __launch_bounds__(256) void attn_pass(
    const bf16* __restrict__ Q, const bf16* __restrict__ Kb, const bf16* __restrict__ Vb,
    bf16* __restrict__ Obase)
{
    __shared__ bf16 pls[4][16][40];

    int hl   = blockIdx.x;
    int qt   = (gridDim.y - 1) - blockIdx.y;
    int tid  = threadIdx.x;
    int wave = tid >> 6;
    int lane = tid & 63;
    int l15  = lane & 15;
    int quad = lane >> 4;

    int q0 = qt * 64 + wave * 16;
    int qg = q0 + l15;

    const bf16* qptr = Q + ((size_t)hl * Ss + qg) * HD + quad * 8;
    bf16x8 qf[4];
#pragma unroll
    for (int s = 0; s < 4; s++) qf[s] = *(const bf16x8*)(qptr + s * 32);

    float m = -1e30f, l = 0.0f;
    floatx4 ctx[8] = {};
    const float scale = 0.08838834764831845f;

    for (int kb = 0; kb <= q0 + 15; kb += 32) {
        floatx4 s0 = {0.f,0.f,0.f,0.f}, s1 = {0.f,0.f,0.f,0.f};
        const bf16* kp0 = Kb + ((size_t)hl * Ss + kb + l15) * HD + quad * 8;
        const bf16* kp1 = kp0 + (size_t)16 * HD;
#pragma unroll
        for (int s = 0; s < 4; s++) {
            bf16x8 k0 = *(const bf16x8*)(kp0 + s * 32);
            bf16x8 k1 = *(const bf16x8*)(kp1 + s * 32);
            s0 = __builtin_amdgcn_mfma_f32_16x16x32_bf16(k0, qf[s], s0, 0, 0, 0);
            s1 = __builtin_amdgcn_mfma_f32_16x16x32_bf16(k1, qf[s], s1, 0, 0, 0);
        }

        float v0[4], v1[4];
#pragma unroll
        for (int r = 0; r < 4; r++) {
            int key0 = kb + quad * 4 + r;
            v0[r] = (key0 > qg)      ? -1e9f : s0[r] * scale;
            v1[r] = (key0 + 16 > qg) ? -1e9f : s1[r] * scale;
        }
        float tmax = fmaxf(fmaxf(fmaxf(v0[0], v0[1]), fmaxf(v0[2], v0[3])),
                           fmaxf(fmaxf(v1[0], v1[1]), fmaxf(v1[2], v1[3])));
        tmax = fmaxf(tmax, __shfl_xor(tmax, 16));
        tmax = fmaxf(tmax, __shfl_xor(tmax, 32));
        float mnew  = fmaxf(m, tmax);
        float alpha = __expf(m - mnew);
        float p0[4], p1[4], tsum = 0.0f;
#pragma unroll
        for (int r = 0; r < 4; r++) {
            p0[r] = __expf(v0[r] - mnew);
            p1[r] = __expf(v1[r] - mnew);
            tsum += p0[r] + p1[r];
        }
        tsum += __shfl_xor(tsum, 16);
        tsum += __shfl_xor(tsum, 32);
        l = l * alpha + tsum;
        m = mnew;
#pragma unroll
        for (int t = 0; t < 8; t++) {
            ctx[t][0] *= alpha; ctx[t][1] *= alpha;
            ctx[t][2] *= alpha; ctx[t][3] *= alpha;
        }

#pragma unroll
        for (int r = 0; r < 4; r++) {
            pls[wave][l15][quad * 4 + r]      = f2b(p0[r]);
            pls[wave][l15][16 + quad * 4 + r] = f2b(p1[r]);
        }
        bf16x8 pf = *(const bf16x8*)&pls[wave][l15][quad * 8];

        const short* vp = (const short*)(Vb + ((size_t)hl * Ss + kb) * HD);
#pragma unroll
        for (int t = 0; t < 8; t++) {
            bf16x8 vf;
#pragma unroll
            for (int j = 0; j < 8; j++) {
                short sv = vp[(size_t)(quad * 8 + j) * HD + t * 16 + l15];
                vf[j] = __builtin_bit_cast(bf16, sv);
            }
            ctx[t] = __builtin_amdgcn_mfma_f32_16x16x32_bf16(vf, pf, ctx[t], 0, 0, 0);
        }
    }

    float inv = 1.0f / l;
    bf16* op = Obase + (size_t)qg * HID + hl * HD;
#pragma unroll
    for (int t = 0; t < 8; t++) {
        bf16x4 ov;
#pragma unroll
        for (int r = 0; r < 4; r++) ov[r] = f2b(ctx[t][r] * inv);
        *(bf16x4*)(op + t * 16 + quad * 4) = ov;
    }
}

// ---------------------------------------------------------------------------
// Out-projection GEMM: C_f32[M][N] = A_bf16[M][K] @ B_f32[N][K]^T.
// ---------------------------------------------------------------------------
__global__ __launch_bounds__(256) void gemm_out_f32(
    const bf16* __restrict__ A, const float* __restrict__ B,
    float* __restrict__ C, int N, int K)
{
    int tid  = threadIdx.x;
    int lane = tid & 63;
    int wave = tid >> 6;
    int l15  = lane & 15;
    int quad = lane >> 4;
    int m0 = blockIdx.x * 128 + (wave >> 1) * 64;
    int n0 = blockIdx.y * 128 + (wave & 1) * 64;

    floatx4 acc[4][4] = {};
    const bf16*  ap = A + (size_t)(m0 + l15) * K + quad * 8;
    const float* bp = B + (size_t)(n0 + l15) * K + quad * 8;

    for (int k0 = 0; k0 < K; k0 += 32) {
        bf16x8 a[4], b[4];
#pragma unroll
        for (int i = 0; i < 4; i++) {
            a[i] = *(const bf16x8*)(ap + (size_t)i * 16 * K + k0);
            b[i] = load8_f32(bp + (size_t)i * 16 * K + k0);
        }
#pragma unroll
        for (int i = 0; i < 4; i++)
#pragma unroll
            for (int j = 0; j < 4; j++)
                acc[i][j] = __builtin_amdgcn_mfma_f32_16x16x32_bf16(a[i], b[j], acc[i][j], 0, 0, 0);
    }

#pragma unroll
    for (int i = 0; i < 4; i++)
#pragma unroll
        for (int j = 0; j < 4; j++) {
            int row = m0 + i * 16 + quad * 4;
            int col = n0 + j * 16 + l15;
#pragma unroll
            for (int r = 0; r < 4; r++)
                C[(size_t)(row + r) * N + col] = acc[i][j][r];   // f32 output
        }
}

extern "C" void kernel_launch(void* const* d_in, const int* in_sizes, int n_in,
                              void* d_out, int out_size, void* d_ws, size_t ws_size,
                              hipStream_t stream)
{
    // Bind inputs by element count (ordering-proof).
    const float *x = nullptr, *w_qkv = nullptr, *w_o = nullptr;
    const float *t0 = nullptr, *t1 = nullptr;
    for (int i = 0; i < n_in; i++) {
        const float* p = (const float*)d_in[i];
        if      (in_sizes[i] == 12582912) w_qkv = p;
        else if (in_sizes[i] ==  8388608) x     = p;
        else if (in_sizes[i] ==  4194304) w_o   = p;
        else if (in_sizes[i] ==   262144) { if (t0) t1 = p; else t0 = p; }
    }
    float* out = (float*)d_out;     // [B,S,HID] FLOAT32 (reference output dtype)

    // ws plan (<= 16 MiB at all times, proven available):
    //   phase 1: compact q/k/v [HG][Ss][HD] bf16 (12.58 MB)
    //   phase 2: f32 out half-tile [2048][2048] (16.78 MB, exactly 16 MiB)
    const size_t pe = (size_t)HG * Ss * HD;
    bf16* qc = (bf16*)d_ws;
    bf16* kc = qc + pe;
    bf16* vc = kc + pe;
    float* fin = (float*)d_ws;

    // bf16 ctx [4096][2048] staged in the UPPER HALF of d_out (bytes 16.78M..33.55M)
    bf16* ctx = (bf16*)((char*)d_out + (size_t)16777216);

    // 4 passes: (batch, head-group); stream order serializes qc/kc/vc reuse.
    for (int bi = 0; bi < Bb; bi++) {
        const float* xb = x + (size_t)bi * Ss * HID;
        for (int hg = 0; hg < 2; hg++) {
            qkv_rope_pass<<<dim3(Ss / 128, 24), 256, 0, stream>>>(
                xb, w_qkv, t0, t1, qc, kc, vc, hg);
            bf16* Obase = ctx + (size_t)bi * Ss * HID + (size_t)hg * HG * HD;
            attn_pass<<<dim3(HG, Ss / 64), 256, 0, stream>>>(qc, kc, vc, Obase);
        }
    }

    // out-projection in two row-halves (ctx in d_out upper half stays intact
    // until consumed; each half: GEMM -> ws, then d2d copy into place).
    // rows 0..2047:
    gemm_out_f32<<<dim3(16, 16), 256, 0, stream>>>(ctx, w_o, fin, HID, HID);
    hipMemcpyAsync(out, fin, (size_t)2048 * HID * sizeof(float),
                   hipMemcpyDeviceToDevice, stream);
    // rows 2048..4095:
    gemm_out_f32<<<dim3(16, 16), 256, 0, stream>>>(ctx + (size_t)2048 * HID, w_o,
                                                   fin, HID, HID);
    hipMemcpyAsync(out + (size_t)2048 * HID, fin, (size_t)2048 * HID * sizeof(float),
                   hipMemcpyDeviceToDevice, stream);
}

// Round 9
// 584.081 us; speedup vs baseline: 3.4158x; 3.4158x over previous
//
#include <hip/hip_runtime.h>
#include <hip/hip_bf16.h>

typedef __bf16 bf16;
typedef __bf16 bf16x4 __attribute__((ext_vector_type(4)));
typedef __bf16 bf16x8 __attribute__((ext_vector_type(8)));
typedef float floatx4 __attribute__((ext_vector_type(4)));

#define Bb   2
#define Ss   2048
#define HID  2048
#define NH   16
#define HD   128
#define HG   8

typedef __attribute__((address_space(3))) unsigned int lds_u32;
typedef const __attribute__((address_space(1))) unsigned int gbl_u32;

__device__ __forceinline__ float b2f(bf16 h) {
    unsigned short u = __builtin_bit_cast(unsigned short, h);
    unsigned int x = ((unsigned int)u) << 16;
    return __builtin_bit_cast(float, x);
}
__device__ __forceinline__ bf16 f2b(float f) {
    __hip_bfloat16 t = __float2bfloat16(f);
    return __builtin_bit_cast(bf16, t);
}
__device__ __forceinline__ bf16x8 load8_f32(const float* p) {
    float4 u = *(const float4*)p;
    float4 v = *(const float4*)(p + 4);
    bf16x8 r;
    r[0] = f2b(u.x); r[1] = f2b(u.y); r[2] = f2b(u.z); r[3] = f2b(u.w);
    r[4] = f2b(v.x); r[5] = f2b(v.y); r[6] = f2b(v.z); r[7] = f2b(v.w);
    return r;
}
// async global->LDS, 16B per lane; lds base must be wave-uniform
__device__ __forceinline__ void stage16(const bf16* g, bf16* l) {
    __builtin_amdgcn_global_load_lds((gbl_u32*)g, (lds_u32*)l, 16, 0, 0);
}

// ===========================================================================
// PATH A kernels (ws >= 64 MiB)
// ===========================================================================

__global__ __launch_bounds__(256) void cvt_f32_bf16(
    const float* __restrict__ in, bf16* __restrict__ out, int n4)
{
    int idx = blockIdx.x * 256 + threadIdx.x;
    int stride = gridDim.x * 256;
    for (int i = idx; i < n4; i += stride) {
        float4 v = ((const float4*)in)[i];
        bf16x4 o; o[0] = f2b(v.x); o[1] = f2b(v.y); o[2] = f2b(v.z); o[3] = f2b(v.w);
        ((bf16x4*)out)[i] = o;
    }
}

// ---------------------------------------------------------------------------
// Single-dispatch QKV GEMM (m97-style LDS staging) + RoPE + head-split.
// A=xb bf16[4096][2048], B=wqb bf16[6144][2048]. grid=(32,48).
// blockIdx.y: sec = y>>4 (0=q,1=k,2=v), h = y&15. Outputs:
//   q,k: [32][2048][128] (roped)    vT: [32][128][2048] (transposed)
// ---------------------------------------------------------------------------
__global__ __launch_bounds__(256) void qkv_gemm_rope(
    const bf16* __restrict__ xb, const bf16* __restrict__ wqb,
    const float* __restrict__ c0, const float* __restrict__ c1,
    bf16* __restrict__ q, bf16* __restrict__ k, bf16* __restrict__ vT)
{
    __shared__ bf16 As[128 * 32];
    __shared__ bf16 Bs[128 * 32];
    __shared__ bf16 tile[128][132];

    bool c0cos = (c0[0] > 0.5f);
    const float* cosT = c0cos ? c0 : c1;
    const float* sinT = c0cos ? c1 : c0;

    int tid = threadIdx.x, lane = tid & 63, w = tid >> 6;
    int l15 = lane & 15, quad = lane >> 4;
    int m0 = blockIdx.x * 128, n0 = blockIdx.y * 128;
    int mw = (w >> 1) * 64, nw = (w & 1) * 64;

    // staging: wave w covers rows [w*32, w*32+32), two 16-row issues
    int srow = w * 32 + (lane >> 2);
    int scol = (lane & 3) * 8;
    const bf16* ga = xb  + (size_t)(m0 + srow) * HID + scol;
    const bf16* gb = wqb + (size_t)(n0 + srow) * HID + scol;
    bf16* la = As + w * 1024;
    bf16* lb = Bs + w * 1024;

    floatx4 acc[4][4] = {};
    for (int k0 = 0; k0 < HID; k0 += 32) {
        stage16(ga + k0,                    la);
        stage16(ga + (size_t)16 * HID + k0, la + 512);
        stage16(gb + k0,                    lb);
        stage16(gb + (size_t)16 * HID + k0, lb + 512);
        __syncthreads();
        bf16x8 a[4], b[4];
#pragma unroll
        for (int i = 0; i < 4; i++) {
            a[i] = *(const bf16x8*)&As[(mw + i * 16 + l15) * 32 + quad * 8];
            b[i] = *(const bf16x8*)&Bs[(nw + i * 16 + l15) * 32 + quad * 8];
        }
#pragma unroll
        for (int i = 0; i < 4; i++)
#pragma unroll
            for (int j = 0; j < 4; j++)
                acc[i][j] = __builtin_amdgcn_mfma_f32_16x16x32_bf16(a[i], b[j], acc[i][j], 0, 0, 0);
        __syncthreads();
    }

    // acc -> LDS tile (C/D layout: col=l15, row=quad*4+r)
#pragma unroll
    for (int i = 0; i < 4; i++)
#pragma unroll
        for (int j = 0; j < 4; j++) {
            int row_l = mw + i * 16 + quad * 4;
            int col_l = nw + j * 16 + l15;
#pragma unroll
            for (int r = 0; r < 4; r++)
                tile[row_l + r][col_l] = f2b(acc[i][j][r]);
        }
    __syncthreads();

    int sec = blockIdx.y >> 4;
    int h   = blockIdx.y & 15;
    int bi  = m0 >> 11;                    // tile never straddles batch
    int bh  = bi * NH + h;
    int sbase = m0 & (Ss - 1);

    if (sec == 2) {
        // transpose-scatter to vT[bh][d][s]
        int d  = tid >> 1;
        int sh = (tid & 1) * 64;
        bf16* vrow = vT + ((size_t)bh * HD + d) * Ss + sbase + sh;
#pragma unroll 4
        for (int i = 0; i < 64; i += 4) {
            bf16x4 pk;
#pragma unroll
            for (int r = 0; r < 4; r++) pk[r] = tile[sh + i + r][d];
            *(bf16x4*)(vrow + i) = pk;
        }
    } else {
        bf16* dst = (sec == 0) ? q : k;
        int d  = tid & 63;
        int r0 = tid >> 6;
#pragma unroll 4
        for (int it = 0; it < 32; it++) {
            int row_l = it * 4 + r0;
            int s = sbase + row_l;
            float x1 = b2f(tile[row_l][d]);
            float x2 = b2f(tile[row_l][d + 64]);
            float cc1 = cosT[s * HD + d];
            float ss1 = sinT[s * HD + d];
            float cc2 = cosT[s * HD + d + 64];
            float ss2 = sinT[s * HD + d + 64];
            size_t o = ((size_t)bh * Ss + s) * HD + d;
            dst[o]      = f2b(x1 * cc1 - x2 * ss1);
            dst[o + 64] = f2b(x2 * cc2 + x1 * ss2);
        }
    }
}

// ---------------------------------------------------------------------------
// Full-grid causal flash attention. Q,K [32][S][HD], VT [32][HD][S].
// ctx (bf16, head-interleaved [4096][HID]) -> O. grid=(32,32), block=256.
// ---------------------------------------------------------------------------
__global__ __launch_bounds__(256) void attn_full(
    const bf16* __restrict__ Q, const bf16* __restrict__ Kb, const bf16* __restrict__ VT,
    bf16* __restrict__ O)
{
    __shared__ bf16 pls[4][16][40];

    int bh   = blockIdx.x;
    int qt   = (gridDim.y - 1) - blockIdx.y;
    int tid  = threadIdx.x;
    int wave = tid >> 6;
    int lane = tid & 63;
    int l15  = lane & 15;
    int quad = lane >> 4;

    int q0 = qt * 64 + wave * 16;
    int qg = q0 + l15;

    const bf16* qptr = Q + ((size_t)bh * Ss + qg) * HD + quad * 8;
    bf16x8 qf[4];
#pragma unroll
    for (int s = 0; s < 4; s++) qf[s] = *(const bf16x8*)(qptr + s * 32);

    float m = -1e30f, l = 0.0f;
    floatx4 ctx[8] = {};
    const float scale = 0.08838834764831845f;
    const bf16* vtb = VT + (size_t)bh * HD * Ss;

    for (int kb = 0; kb <= q0 + 15; kb += 32) {
        floatx4 s0 = {0.f,0.f,0.f,0.f}, s1 = {0.f,0.f,0.f,0.f};
        const bf16* kp0 = Kb + ((size_t)bh * Ss + kb + l15) * HD + quad * 8;
        const bf16* kp1 = kp0 + (size_t)16 * HD;
#pragma unroll
        for (int s = 0; s < 4; s++) {
            bf16x8 k0 = *(const bf16x8*)(kp0 + s * 32);
            bf16x8 k1 = *(const bf16x8*)(kp1 + s * 32);
            s0 = __builtin_amdgcn_mfma_f32_16x16x32_bf16(k0, qf[s], s0, 0, 0, 0);
            s1 = __builtin_amdgcn_mfma_f32_16x16x32_bf16(k1, qf[s], s1, 0, 0, 0);
        }

        float v0[4], v1[4];
#pragma unroll
        for (int r = 0; r < 4; r++) {
            int key0 = kb + quad * 4 + r;
            v0[r] = (key0 > qg)      ? -1e9f : s0[r] * scale;
            v1[r] = (key0 + 16 > qg) ? -1e9f : s1[r] * scale;
        }
        float tmax = fmaxf(fmaxf(fmaxf(v0[0], v0[1]), fmaxf(v0[2], v0[3])),
                           fmaxf(fmaxf(v1[0], v1[1]), fmaxf(v1[2], v1[3])));
        tmax = fmaxf(tmax, __shfl_xor(tmax, 16));
        tmax = fmaxf(tmax, __shfl_xor(tmax, 32));
        float mnew  = fmaxf(m, tmax);
        float alpha = __expf(m - mnew);
        float p0[4], p1[4], tsum = 0.0f;
#pragma unroll
        for (int r = 0; r < 4; r++) {
            p0[r] = __expf(v0[r] - mnew);
            p1[r] = __expf(v1[r] - mnew);
            tsum += p0[r] + p1[r];
        }
        tsum += __shfl_xor(tsum, 16);
        tsum += __shfl_xor(tsum, 32);
        l = l * alpha + tsum;
        m = mnew;
#pragma unroll
        for (int t = 0; t < 8; t++) {
            ctx[t][0] *= alpha; ctx[t][1] *= alpha;
            ctx[t][2] *= alpha; ctx[t][3] *= alpha;
        }

#pragma unroll
        for (int r = 0; r < 4; r++) {
            pls[wave][l15][quad * 4 + r]      = f2b(p0[r]);
            pls[wave][l15][16 + quad * 4 + r] = f2b(p1[r]);
        }
        bf16x8 pf = *(const bf16x8*)&pls[wave][l15][quad * 8];

#pragma unroll
        for (int t = 0; t < 8; t++) {
            bf16x8 vf = *(const bf16x8*)(vtb + (size_t)(t * 16 + l15) * Ss + kb + quad * 8);
            ctx[t] = __builtin_amdgcn_mfma_f32_16x16x32_bf16(vf, pf, ctx[t], 0, 0, 0);
        }
    }

    float inv = 1.0f / l;
    int bi = bh >> 4, h = bh & (NH - 1);
    bf16* op = O + ((size_t)(bi * Ss + qg)) * HID + h * HD;
#pragma unroll
    for (int t = 0; t < 8; t++) {
        bf16x4 ov;
#pragma unroll
        for (int r = 0; r < 4; r++) ov[r] = f2b(ctx[t][r] * inv);
        *(bf16x4*)(op + t * 16 + quad * 4) = ov;
    }
}

// ---------------------------------------------------------------------------
// Out-projection (m97-style): C_f32[4096][2048] = ctx_bf16 @ wob_bf16^T
// ---------------------------------------------------------------------------
__global__ __launch_bounds__(256) void out_gemm(
    const bf16* __restrict__ A, const bf16* __restrict__ B, float* __restrict__ C)
{
    __shared__ bf16 As[128 * 32];
    __shared__ bf16 Bs[128 * 32];

    int tid = threadIdx.x, lane = tid & 63, w = tid >> 6;
    int l15 = lane & 15, quad = lane >> 4;
    int m0 = blockIdx.x * 128, n0 = blockIdx.y * 128;
    int mw = (w >> 1) * 64, nw = (w & 1) * 64;

    int srow = w * 32 + (lane >> 2);
    int scol = (lane & 3) * 8;
    const bf16* ga = A + (size_t)(m0 + srow) * HID + scol;
    const bf16* gb = B + (size_t)(n0 + srow) * HID + scol;
    bf16* la = As + w * 1024;
    bf16* lb = Bs + w * 1024;

    floatx4 acc[4][4] = {};
    for (int k0 = 0; k0 < HID; k0 += 32) {
        stage16(ga + k0,                    la);
        stage16(ga + (size_t)16 * HID + k0, la + 512);
        stage16(gb + k0,                    lb);
        stage16(gb + (size_t)16 * HID + k0, lb + 512);
        __syncthreads();
        bf16x8 a[4], b[4];
#pragma unroll
        for (int i = 0; i < 4; i++) {
            a[i] = *(const bf16x8*)&As[(mw + i * 16 + l15) * 32 + quad * 8];
            b[i] = *(const bf16x8*)&Bs[(nw + i * 16 + l15) * 32 + quad * 8];
        }
#pragma unroll
        for (int i = 0; i < 4; i++)
#pragma unroll
            for (int j = 0; j < 4; j++)
                acc[i][j] = __builtin_amdgcn_mfma_f32_16x16x32_bf16(a[i], b[j], acc[i][j], 0, 0, 0);
        __syncthreads();
    }

#pragma unroll
    for (int i = 0; i < 4; i++)
#pragma unroll
        for (int j = 0; j < 4; j++) {
            int row = m0 + mw + i * 16 + quad * 4;
            int col = n0 + nw + j * 16 + l15;
#pragma unroll
            for (int r = 0; r < 4; r++)
                C[(size_t)(row + r) * HID + col] = acc[i][j][r];
        }
}

// ===========================================================================
// PATH B kernels (round-8 fallback, ws < 64 MiB) — proven passing
// ===========================================================================

__global__ __launch_bounds__(256) void qkv_rope_pass(
    const float* __restrict__ xb, const float* __restrict__ W,
    const float* __restrict__ c0, const float* __restrict__ c1,
    bf16* __restrict__ qc, bf16* __restrict__ kc, bf16* __restrict__ vc, int hg)
{
    __shared__ bf16 tile[128][132];
    bool c0cos = (c0[0] > 0.5f);
    const float* cosT = c0cos ? c0 : c1;
    const float* sinT = c0cos ? c1 : c0;

    int tid = threadIdx.x, lane = tid & 63, wave = tid >> 6;
    int l15 = lane & 15, quad = lane >> 4;
    int sec = blockIdx.y >> 3, hl = blockIdx.y & 7;
    int nbase = sec * (NH * HD) + (hg * HG + hl) * HD;
    int m0 = blockIdx.x * 128 + (wave >> 1) * 64;
    int n0l = (wave & 1) * 64;

    floatx4 acc[4][4] = {};
    const float* ap = xb + (size_t)(m0 + l15) * HID + quad * 8;
    const float* bp = W  + (size_t)(nbase + n0l + l15) * HID + quad * 8;
    for (int k0 = 0; k0 < HID; k0 += 32) {
        bf16x8 a[4], b[4];
#pragma unroll
        for (int i = 0; i < 4; i++) {
            a[i] = load8_f32(ap + (size_t)i * 16 * HID + k0);
            b[i] = load8_f32(bp + (size_t)i * 16 * HID + k0);
        }
#pragma unroll
        for (int i = 0; i < 4; i++)
#pragma unroll
            for (int j = 0; j < 4; j++)
                acc[i][j] = __builtin_amdgcn_mfma_f32_16x16x32_bf16(a[i], b[j], acc[i][j], 0, 0, 0);
    }
    int lr = (wave >> 1) * 64;
#pragma unroll
    for (int i = 0; i < 4; i++)
#pragma unroll
        for (int j = 0; j < 4; j++) {
            int row_l = lr + i * 16 + quad * 4;
            int col_l = n0l + j * 16 + l15;
#pragma unroll
            for (int r = 0; r < 4; r++)
                tile[row_l + r][col_l] = f2b(acc[i][j][r]);
        }
    __syncthreads();

    bf16* dst = (sec == 0) ? qc : (sec == 1) ? kc : vc;
    int d = tid & 63, r0 = tid >> 6;
#pragma unroll 4
    for (int it = 0; it < 32; it++) {
        int row_l = it * 4 + r0;
        int s = blockIdx.x * 128 + row_l;
        float x1 = b2f(tile[row_l][d]);
        float x2 = b2f(tile[row_l][d + 64]);
        size_t o = ((size_t)hl * Ss + s) * HD + d;
        if (sec == 2) { dst[o] = f2b(x1); dst[o + 64] = f2b(x2); }
        else {
            float cc1 = cosT[s * HD + d], ss1 = sinT[s * HD + d];
            float cc2 = cosT[s * HD + d + 64], ss2 = sinT[s * HD + d + 64];
            dst[o]      = f2b(x1 * cc1 - x2 * ss1);
            dst[o + 64] = f2b(x2 * cc2 + x1 * ss2);
        }
    }
}

__global__ __launch_bounds__(256) void attn_pass(
    const bf16* __restrict__ Q, const bf16* __restrict__ Kb, const bf16* __restrict__ Vb,
    bf16* __restrict__ Obase)
{
    __shared__ bf16 pls[4][16][40];
    int hl = blockIdx.x;
    int qt = (gridDim.y - 1) - blockIdx.y;
    int tid = threadIdx.x, wave = tid >> 6, lane = tid & 63;
    int l15 = lane & 15, quad = lane >> 4;
    int q0 = qt * 64 + wave * 16;
    int qg = q0 + l15;

    const bf16* qptr = Q + ((size_t)hl * Ss + qg) * HD + quad * 8;
    bf16x8 qf[4];
#pragma unroll
    for (int s = 0; s < 4; s++) qf[s] = *(const bf16x8*)(qptr + s * 32);

    float m = -1e30f, l = 0.0f;
    floatx4 ctx[8] = {};
    const float scale = 0.08838834764831845f;

    for (int kb = 0; kb <= q0 + 15; kb += 32) {
        floatx4 s0 = {0.f,0.f,0.f,0.f}, s1 = {0.f,0.f,0.f,0.f};
        const bf16* kp0 = Kb + ((size_t)hl * Ss + kb + l15) * HD + quad * 8;
        const bf16* kp1 = kp0 + (size_t)16 * HD;
#pragma unroll
        for (int s = 0; s < 4; s++) {
            bf16x8 k0 = *(const bf16x8*)(kp0 + s * 32);
            bf16x8 k1 = *(const bf16x8*)(kp1 + s * 32);
            s0 = __builtin_amdgcn_mfma_f32_16x16x32_bf16(k0, qf[s], s0, 0, 0, 0);
            s1 = __builtin_amdgcn_mfma_f32_16x16x32_bf16(k1, qf[s], s1, 0, 0, 0);
        }
        float v0[4], v1[4];
#pragma unroll
        for (int r = 0; r < 4; r++) {
            int key0 = kb + quad * 4 + r;
            v0[r] = (key0 > qg)      ? -1e9f : s0[r] * scale;
            v1[r] = (key0 + 16 > qg) ? -1e9f : s1[r] * scale;
        }
        float tmax = fmaxf(fmaxf(fmaxf(v0[0], v0[1]), fmaxf(v0[2], v0[3])),
                           fmaxf(fmaxf(v1[0], v1[1]), fmaxf(v1[2], v1[3])));
        tmax = fmaxf(tmax, __shfl_xor(tmax, 16));
        tmax = fmaxf(tmax, __shfl_xor(tmax, 32));
        float mnew = fmaxf(m, tmax);
        float alpha = __expf(m - mnew);
        float p0[4], p1[4], tsum = 0.0f;
#pragma unroll
        for (int r = 0; r < 4; r++) {
            p0[r] = __expf(v0[r] - mnew);
            p1[r] = __expf(v1[r] - mnew);
            tsum += p0[r] + p1[r];
        }
        tsum += __shfl_xor(tsum, 16);
        tsum += __shfl_xor(tsum, 32);
        l = l * alpha + tsum;
        m = mnew;
#pragma unroll
        for (int t = 0; t < 8; t++) {
            ctx[t][0] *= alpha; ctx[t][1] *= alpha;
            ctx[t][2] *= alpha; ctx[t][3] *= alpha;
        }
#pragma unroll
        for (int r = 0; r < 4; r++) {
            pls[wave][l15][quad * 4 + r]      = f2b(p0[r]);
            pls[wave][l15][16 + quad * 4 + r] = f2b(p1[r]);
        }
        bf16x8 pf = *(const bf16x8*)&pls[wave][l15][quad * 8];
        const short* vp = (const short*)(Vb + ((size_t)hl * Ss + kb) * HD);
#pragma unroll
        for (int t = 0; t < 8; t++) {
            bf16x8 vf;
#pragma unroll
            for (int j = 0; j < 8; j++) {
                short sv = vp[(size_t)(quad * 8 + j) * HD + t * 16 + l15];
                vf[j] = __builtin_bit_cast(bf16, sv);
            }
            ctx[t] = __builtin_amdgcn_mfma_f32_16x16x32_bf16(vf, pf, ctx[t], 0, 0, 0);
        }
    }
    float inv = 1.0f / l;
    bf16* op = Obase + (size_t)qg * HID + hl * HD;
#pragma unroll
    for (int t = 0; t < 8; t++) {
        bf16x4 ov;
#pragma unroll
        for (int r = 0; r < 4; r++) ov[r] = f2b(ctx[t][r] * inv);
        *(bf16x4*)(op + t * 16 + quad * 4) = ov;
    }
}

__global__ __launch_bounds__(256) void gemm_out_f32(
    const bf16* __restrict__ A, const float* __restrict__ B,
    float* __restrict__ C, int N, int K)
{
    int tid = threadIdx.x, lane = tid & 63, wave = tid >> 6;
    int l15 = lane & 15, quad = lane >> 4;
    int m0 = blockIdx.x * 128 + (wave >> 1) * 64;
    int n0 = blockIdx.y * 128 + (wave & 1) * 64;

    floatx4 acc[4][4] = {};
    const bf16*  ap = A + (size_t)(m0 + l15) * K + quad * 8;
    const float* bp = B + (size_t)(n0 + l15) * K + quad * 8;
    for (int k0 = 0; k0 < K; k0 += 32) {
        bf16x8 a[4], b[4];
#pragma unroll
        for (int i = 0; i < 4; i++) {
            a[i] = *(const bf16x8*)(ap + (size_t)i * 16 * K + k0);
            b[i] = load8_f32(bp + (size_t)i * 16 * K + k0);
        }
#pragma unroll
        for (int i = 0; i < 4; i++)
#pragma unroll
            for (int j = 0; j < 4; j++)
                acc[i][j] = __builtin_amdgcn_mfma_f32_16x16x32_bf16(a[i], b[j], acc[i][j], 0, 0, 0);
    }
#pragma unroll
    for (int i = 0; i < 4; i++)
#pragma unroll
        for (int j = 0; j < 4; j++) {
            int row = m0 + i * 16 + quad * 4;
            int col = n0 + j * 16 + l15;
#pragma unroll
            for (int r = 0; r < 4; r++)
                C[(size_t)(row + r) * N + col] = acc[i][j][r];
        }
}

extern "C" void kernel_launch(void* const* d_in, const int* in_sizes, int n_in,
                              void* d_out, int out_size, void* d_ws, size_t ws_size,
                              hipStream_t stream)
{
    const float *x = nullptr, *w_qkv = nullptr, *w_o = nullptr;
    const float *t0 = nullptr, *t1 = nullptr;
    for (int i = 0; i < n_in; i++) {
        const float* p = (const float*)d_in[i];
        if      (in_sizes[i] == 12582912) w_qkv = p;
        else if (in_sizes[i] ==  8388608) x     = p;
        else if (in_sizes[i] ==  4194304) w_o   = p;
        else if (in_sizes[i] ==   262144) { if (t0) t1 = p; else t0 = p; }
    }
    float* out = (float*)d_out;
    char* ws = (char*)d_ws;

    if (ws_size >= (size_t)67108864) {
        // ---------------- PATH A ----------------
        bf16* xb  = (bf16*)ws;                       // 16.78 MB
        bf16* wqb = (bf16*)(ws + 16777216);          // 25.17 MB
        bf16* wob = (bf16*)(ws + 41943040);          // 8.39 MB
        bf16* ctx = (bf16*)ws;                       // reuse xb after qkv
        bf16 *qb, *kbuf, *vT;
        if (ws_size >= (size_t)100663296) {          // A1: all in ws
            qb   = (bf16*)(ws + 50331648);
            kbuf = (bf16*)(ws + 67108864);
            vT   = (bf16*)(ws + 83886080);
        } else {                                     // A2: q,k in d_out scratch
            qb   = (bf16*)d_out;
            kbuf = (bf16*)((char*)d_out + 16777216);
            vT   = (bf16*)(ws + 50331648);
        }

        cvt_f32_bf16<<<2048, 256, 0, stream>>>(x,     xb,  8388608 / 4);
        cvt_f32_bf16<<<2048, 256, 0, stream>>>(w_qkv, wqb, 12582912 / 4);
        cvt_f32_bf16<<<1024, 256, 0, stream>>>(w_o,   wob, 4194304 / 4);

        qkv_gemm_rope<<<dim3(32, 48), 256, 0, stream>>>(xb, wqb, t0, t1, qb, kbuf, vT);
        attn_full<<<dim3(Bb * NH, Ss / 64), 256, 0, stream>>>(qb, kbuf, vT, ctx);
        out_gemm<<<dim3(32, 16), 256, 0, stream>>>(ctx, wob, out);
    } else {
        // ---------------- PATH B (round-8 fallback) ----------------
        const size_t pe = (size_t)HG * Ss * HD;
        bf16* qc = (bf16*)d_ws;
        bf16* kc = qc + pe;
        bf16* vc = kc + pe;
        float* fin = (float*)d_ws;
        bf16* ctx = (bf16*)((char*)d_out + (size_t)16777216);

        for (int bi = 0; bi < Bb; bi++) {
            const float* xbp = x + (size_t)bi * Ss * HID;
            for (int hg = 0; hg < 2; hg++) {
                qkv_rope_pass<<<dim3(Ss / 128, 24), 256, 0, stream>>>(
                    xbp, w_qkv, t0, t1, qc, kc, vc, hg);
                bf16* Obase = ctx + (size_t)bi * Ss * HID + (size_t)hg * HG * HD;
                attn_pass<<<dim3(HG, Ss / 64), 256, 0, stream>>>(qc, kc, vc, Obase);
            }
        }
        gemm_out_f32<<<dim3(16, 16), 256, 0, stream>>>(ctx, w_o, fin, HID, HID);
        hipMemcpyAsync(out, fin, (size_t)2048 * HID * sizeof(float),
                       hipMemcpyDeviceToDevice, stream);
        gemm_out_f32<<<dim3(16, 16), 256, 0, stream>>>(ctx + (size_t)2048 * HID, w_o,
                                                       fin, HID, HID);
        hipMemcpyAsync(out + (size_t)2048 * HID, fin, (size_t)2048 * HID * sizeof(float),
                       hipMemcpyDeviceToDevice, stream);
    }
}